// Round 7
// baseline (959.773 us; speedup 1.0000x reference)
//
#include <hip/hip_runtime.h>
#include <cstdint>

#define NROWS 16384
#define FDIM 64
#define HDIM 128
#define ODIM 512
#define KDIM 8192
#define NSTEPS 64   // k-steps per block (split-K x2: 64 * 64 = 4096)

#define BM 256
#define BN 256
#define BK 64

typedef short bf16x8 __attribute__((ext_vector_type(8)));
typedef float f32x4 __attribute__((ext_vector_type(4)));
typedef uint32_t u32x4 __attribute__((ext_vector_type(4)));

__device__ __forceinline__ uint16_t rne_bf16(float f) {
  uint32_t u = __builtin_bit_cast(uint32_t, f);
  u += 0x7fffu + ((u >> 16) & 1u);
  return (uint16_t)(u >> 16);
}

// ---- pre-kernel 1: W2 [K=8192][O=512] f32 -> W2F fragment-linear bf16 ----
// Entry e (16B = one lane's 8 k-elems of one 16x16x32 B-fragment):
//   lane=e&63, nt=(e>>6)&3, kc=(e>>8)&1, ws=(e>>9)&7, kstep=(e>>12)&127
//   col = ws*64 + nt*16 + (lane&15)
//   k0  = kstep*64 + kc*32 + (lane>>4)*8     (B-frag: col=lane&15, k=(lane>>4)*8+j)
// Wave ws at kstep reads its 8 frags (kc,nt) as one contiguous 8KB block.
__global__ void prep_w2f(const float* __restrict__ W2, uint16_t* __restrict__ W2F) {
  const int e = blockIdx.x * 256 + threadIdx.x;  // 2048*256 = 524288 = 2^19
  const int lane = e & 63;
  const int nt = (e >> 6) & 3;
  const int kc = (e >> 8) & 1;
  const int ws = (e >> 9) & 7;
  const int kstep = (e >> 12) & 127;
  const int col = ws * 64 + nt * 16 + (lane & 15);
  const int k0 = kstep * 64 + kc * 32 + (lane >> 4) * 8;
  uint16_t v[8];
#pragma unroll
  for (int j = 0; j < 8; ++j) v[j] = rne_bf16(W2[(size_t)(k0 + j) * ODIM + col]);
  *(u32x4*)(W2F + (size_t)e * 8) = *(u32x4*)v;
}

// ---- pre-kernel 2: b2sum[o] = sum_f b2[f][o] ----
__global__ void prep_small(const float* __restrict__ b2, float* __restrict__ b2sum) {
  const int t = blockIdx.x * 256 + threadIdx.x;  // 2*256 = 512
  float s = 0.f;
#pragma unroll
  for (int f = 0; f < FDIM; ++f) s += b2[(size_t)f * ODIM + t];
  b2sum[t] = s;
}

// ---- main kernel ----
// BM=256 x BN=256 (elu recompute x2), split-K x2: grid 256 = 1 block/CU.
// 512 thr = 8 waves as (wm=wid>>2) x (wn=wid&3): wave-tile 128m x 64n.
// B: fragment-linear global->VGPR (dbuf'd, prefetched 1 step). LDS: A only,
// 2 x 32KB dbuf, ONE barrier/step. B traffic: 256 blocks x 2MB = 512MB.
// bid%8 -> XCD round-robin keeps (oh,kh) constant per XCD => 2MB L2-resident B.
// 16x16x32 MFMA + R1-R5 swizzles (measured 0 bank conflicts).
__global__ __launch_bounds__(512, 1) void mlp_gemm(
    const float* __restrict__ x, const float* __restrict__ W1,
    const float* __restrict__ b1, const uint16_t* __restrict__ W2F,
    const float* __restrict__ b2sum, float* __restrict__ out) {
  __shared__ __align__(16) uint16_t As[2][BM * BK];  // 2 x 32 KB

  const int tid = threadIdx.x;
  const int bid = blockIdx.x;
  const int oh = bid & 1;          // O-half (256 cols)
  const int kh = (bid >> 1) & 1;   // K-half (4096 k)
  const int m0 = (bid >> 2) * BM;

  const int wid = tid >> 6;
  const int lane = tid & 63;
  const int wm = wid >> 2;         // wave row-half (128 rows)
  const int wn = wid & 3;          // wave col-slice (64 cols)
  const int q = lane >> 4;
  const int r = lane & 15;

  // A-gen roles (R5-proven, 0 conflicts): 2 threads/row, 4 col-groups each
  const int arow = tid >> 1;            // 0..255
  const int gbase = (tid & 1) * 4;      // col-groups gbase..gbase+3

  // wave-uniform fragment-linear B base (element units); ws = oh*4 + wn
  const uint16_t* wfbase =
      W2F + (size_t)(oh * 4 + wn) * 4096 + (size_t)lane * 8;

  f32x4 acc[8][4];
#pragma unroll
  for (int i = 0; i < 8; ++i)
#pragma unroll
    for (int j = 0; j < 4; ++j) acc[i][j] = {0.f, 0.f, 0.f, 0.f};

  auto loadB = [&](int s, bf16x8 (&rb)[8]) {
    const uint16_t* p = wfbase + (size_t)(kh * 64 + s) * 32768;
#pragma unroll
    for (int j = 0; j < 8; ++j)          // j = kc*4 + nt, contiguous 8KB
      rb[j] = *(const bf16x8*)(p + j * 512);
  };

  auto genA = [&](int s, int buf) {
    const int kstep = kh * 64 + s;
    const int f = kstep >> 1;
    const int h0 = (kstep & 1) * 64;
    const float xv = x[(size_t)(m0 + arow) * FDIM + f];
    const float* w1p = W1 + f * HDIM + h0;  // wave-uniform rows: L1 broadcast
    const float* b1p = b1 + f * HDIM + h0;
    uint16_t* ap = &As[buf][arow * BK];
#pragma unroll
    for (int gi = 0; gi < 4; ++gi) {
      const int g = gbase + gi;
      float wv[8], bv[8];
      *(f32x4*)&wv[0] = *(const f32x4*)(w1p + g * 8);
      *(f32x4*)&wv[4] = *(const f32x4*)(w1p + g * 8 + 4);
      *(f32x4*)&bv[0] = *(const f32x4*)(b1p + g * 8);
      *(f32x4*)&bv[4] = *(const f32x4*)(b1p + g * 8 + 4);
      u32x4 ov;
#pragma unroll
      for (int p = 0; p < 4; ++p) {
        float p0 = fmaf(xv, wv[2 * p], bv[2 * p]);
        float p1 = fmaf(xv, wv[2 * p + 1], bv[2 * p + 1]);
        float r0 = fmaxf(p0, 0.f) + fminf(__expf(p0) - 1.f, 0.f);
        float r1 = fmaxf(p1, 0.f) + fminf(__expf(p1) - 1.f, 0.f);
        ov[p] = __builtin_amdgcn_perm(__builtin_bit_cast(uint32_t, r1),
                                      __builtin_bit_cast(uint32_t, r0),
                                      0x07060302u);
      }
      *(u32x4*)(ap + ((g ^ (arow & 7)) * 8)) = ov;  // XOR-swizzled 16B groups
    }
  };

  auto domfma = [&](int buf, bf16x8 (&rb)[8]) {
#pragma unroll
    for (int kc = 0; kc < 2; ++kc) {
      const int cg = kc * 4 + q;
      bf16x8 af[8];
#pragma unroll
      for (int mt = 0; mt < 8; ++mt) {
        const int row = wm * 128 + mt * 16 + r;
        af[mt] = *(const bf16x8*)&As[buf][row * BK + ((cg ^ (row & 7)) * 8)];
      }
#pragma unroll
      for (int nt = 0; nt < 4; ++nt)
#pragma unroll
        for (int mt = 0; mt < 8; ++mt)
          acc[mt][nt] = __builtin_amdgcn_mfma_f32_16x16x32_bf16(
              af[mt], rb[kc * 4 + nt], acc[mt][nt], 0, 0, 0);
    }
  };

  bf16x8 rb0[8], rb1[8];
  loadB(0, rb0);
  genA(0, 0);

  for (int s = 0; s < NSTEPS; s += 2) {
    __syncthreads();                  // As[0](s) ready; As[1] free
    loadB(s + 1, rb1);                // B(s+1) in flight under this step
    if (wm == 0) { genA(s + 1, 1); domfma(0, rb0); }
    else         { domfma(0, rb0); genA(s + 1, 1); }
    __syncthreads();                  // As[1](s+1) ready; As[0] free
    if (s + 2 < NSTEPS) {
      loadB(s + 2, rb0);
      if (wm == 0) { genA(s + 2, 0); domfma(1, rb1); }
      else         { domfma(1, rb1); genA(s + 2, 0); }
    } else {
      domfma(1, rb1);
    }
  }

  // ---- epilogue: split-K atomic accumulate (out pre-zeroed); kh=0 adds bias ----
  const int o0 = oh * 256 + wn * 64;
#pragma unroll
  for (int nt = 0; nt < 4; ++nt) {
    const int col = o0 + nt * 16 + r;
    const float bias = (kh == 0) ? b2sum[col] * 0.125f : 0.f;
#pragma unroll
    for (int mt = 0; mt < 8; ++mt)
#pragma unroll
      for (int v = 0; v < 4; ++v) {
        const int row = m0 + wm * 128 + mt * 16 + q * 4 + v;  // C/D: row=quad*4+reg
        unsafeAtomicAdd(&out[(size_t)row * ODIM + col],
                        acc[mt][nt][v] * 0.125f + bias);
      }
  }
}

extern "C" void kernel_launch(void* const* d_in, const int* in_sizes, int n_in,
                              void* d_out, int out_size, void* d_ws, size_t ws_size,
                              hipStream_t stream) {
  const float* x  = (const float*)d_in[0];
  const float* W1 = (const float*)d_in[1];
  const float* b1 = (const float*)d_in[2];
  const float* W2 = (const float*)d_in[3];
  const float* b2 = (const float*)d_in[4];
  float* out = (float*)d_out;

  char* ws = (char*)d_ws;
  float*    b2sum = (float*)ws;                 // 2KB
  uint16_t* W2F   = (uint16_t*)(ws + 4096);     // 8MB fragment-linear bf16

  hipMemsetAsync(out, 0, (size_t)NROWS * ODIM * sizeof(float), stream);
  prep_w2f<<<2048, 256, 0, stream>>>(W2, W2F);
  prep_small<<<2, 256, 0, stream>>>(b2, b2sum);
  // grid 256 = 64 m-blocks x 2 o-halves x 2 k-halves = 1 block/CU
  mlp_gemm<<<256, 512, 0, stream>>>(x, W1, b1, W2F, b2sum, out);
}